// Round 4
// baseline (147.601 us; speedup 1.0000x reference)
//
#include <hip/hip_runtime.h>
#include <math.h>

#define SEQ 5
#define EMBC 64   // EMB == CLUSTER == 64

typedef float4 f4;

// reductions within a 16-lane subgroup (wave64 = 4 subgroups of 16)
__device__ __forceinline__ float sub_sum(float v) {
    #pragma unroll
    for (int o = 8; o > 0; o >>= 1) v += __shfl_xor(v, o, 64);
    return v;
}
__device__ __forceinline__ float sub_max(float v) {
    #pragma unroll
    for (int o = 8; o > 0; o >>= 1) v = fmaxf(v, __shfl_xor(v, o, 64));
    return v;
}
__device__ __forceinline__ float wave_max64(float v) {
    #pragma unroll
    for (int o = 32; o > 0; o >>= 1) v = fmaxf(v, __shfl_xor(v, o, 64));
    return v;
}
__device__ __forceinline__ float wave_sum64(float v) {
    #pragma unroll
    for (int o = 32; o > 0; o >>= 1) v += __shfl_xor(v, o, 64);
    return v;
}
__device__ __forceinline__ float dot4(f4 a, f4 b) {
    return fmaf(a.x, b.x, fmaf(a.y, b.y, fmaf(a.z, b.z, a.w * b.w)));
}
__device__ __forceinline__ f4 fma4(f4 a, float s, f4 c) {
    f4 r; r.x = fmaf(a.x, s, c.x); r.y = fmaf(a.y, s, c.y);
          r.z = fmaf(a.z, s, c.z); r.w = fmaf(a.w, s, c.w); return r;
}
// row softmax of a 64-float vector distributed as float4 over a 16-lane subgroup
__device__ __forceinline__ f4 sub_softmax(f4 a, float scale) {
    a.x *= scale; a.y *= scale; a.z *= scale; a.w *= scale;
    const float m = sub_max(fmaxf(fmaxf(a.x, a.y), fmaxf(a.z, a.w)));
    f4 e; e.x = __expf(a.x - m); e.y = __expf(a.y - m);
          e.z = __expf(a.z - m); e.w = __expf(a.w - m);
    const float inv = 1.0f / sub_sum(((e.x + e.y) + (e.z + e.w)));
    e.x *= inv; e.y *= inv; e.z *= inv; e.w *= inv;
    return e;
}

// ---- Kernel A: column-softmax of w_raw*500 (axis=0), stored TRANSPOSED ----
// block d (64 blocks), lane c: wT[d*64+c] = softmax_c(w_raw[:,d]*500)[c]
__global__ __launch_bounds__(64) void wprep_kernel(
    const float* __restrict__ w_raw, float* __restrict__ wT)
{
    const int d = blockIdx.x;
    const int c = threadIdx.x;
    float x = w_raw[c * EMBC + d] * 500.0f;
    const float m = wave_max64(x);
    const float e = __expf(x - m);
    const float s = wave_sum64(e);
    wT[d * EMBC + c] = e / s;   // coalesced write
}

// ---- Kernel B: V[b] = w @ softmax(ae[y_b]*50)  with wT register-resident ----
// lane = output cluster c; wc[d] = w[c][d] (64 coalesced dword loads, L1-hot).
// aey rows gathered/softmaxed in subgroup-f4 layout, broadcast via LDS.
__global__ __launch_bounds__(256) void vprep_kernel(
    const int* __restrict__ y_idx, const float* __restrict__ ae_raw,
    const float* __restrict__ wT, float* __restrict__ V, int B)
{
    __shared__ float s_aey[4 * 4 * EMBC];   // [wave][sub][64]

    const int t    = threadIdx.x;
    const int wave = t >> 6;
    const int lane = t & 63;
    const int sub  = lane >> 4;
    const int sl   = lane & 15;

    // register-resident w column for c = lane: wc[d] = wT[d*64 + lane]
    float wc[EMBC];
    #pragma unroll
    for (int d = 0; d < EMBC; ++d) wc[d] = wT[d * EMBC + lane];

    // gather + softmax one aey row per subgroup
    int b = (blockIdx.x * 4 + wave) * 4 + sub;
    int bc = (b < B) ? b : (B - 1);
    const int yi = y_idx[bc];
    f4 aey = ((const f4*)ae_raw)[yi * 16 + sl];
    aey = sub_softmax(aey, 50.0f);
    ((f4*)&s_aey[(wave * 4 + sub) * EMBC])[sl] = aey;
    __syncthreads();

    // each lane computes v[c=lane] for the wave's 4 batch elements
    #pragma unroll
    for (int bb = 0; bb < 4; ++bb) {
        const f4* a4 = (const f4*)&s_aey[(wave * 4 + bb) * EMBC];
        float v = 0.0f;
        #pragma unroll
        for (int dd = 0; dd < 16; ++dd) {
            const f4 a = a4[dd];               // broadcast ds_read_b128
            v = fmaf(wc[4 * dd + 0], a.x, v);
            v = fmaf(wc[4 * dd + 1], a.y, v);
            v = fmaf(wc[4 * dd + 2], a.z, v);
            v = fmaf(wc[4 * dd + 3], a.w, v);
        }
        const int vb = (blockIdx.x * 4 + wave) * 4 + bb;
        if (vb < B) V[vb * EMBC + lane] = v;   // coalesced
    }
}

// ---- Kernel C: main — 16-lane subgroup per b; V[b] is one coalesced f4 ----
__global__ __launch_bounds__(256) void rumc_main(
    const int* __restrict__ u_idx, const int* __restrict__ X_idx,
    const int* __restrict__ y_idx,
    const float* __restrict__ item_emb, const float* __restrict__ user_emb,
    const float* __restrict__ ae_raw, const float* __restrict__ V,
    float* __restrict__ out, int B)
{
    const int t    = threadIdx.x;
    const int wave = t >> 6;
    const int lane = t & 63;
    const int sub  = lane >> 4;
    const int sl   = lane & 15;

    int b = (blockIdx.x * 4 + wave) * 4 + sub;
    const bool live = (b < B);
    if (!live) b = B - 1;

    const int yi = y_idx[b];
    const int ui = u_idx[b];
    int xi[SEQ];
    #pragma unroll
    for (int s = 0; s < SEQ; ++s) xi[s] = X_idx[b * SEQ + s];

    const f4* __restrict__ item4 = (const f4*)item_emb;
    const f4* __restrict__ user4 = (const f4*)user_emb;
    const f4* __restrict__ ae4   = (const f4*)ae_raw;

    // all row gathers up front (independent 1 KB/wave loads)
    f4 v4 = ((const f4*)V)[b * 16 + sl];
    f4 ax[SEQ];
    #pragma unroll
    for (int s = 0; s < SEQ; ++s) ax[s] = ae4[xi[s] * 16 + sl];
    f4 ye = item4[yi * 16 + sl];
    f4 xe[SEQ];
    #pragma unroll
    for (int s = 0; s < SEQ; ++s) xe[s] = item4[xi[s] * 16 + sl];
    f4 ue = user4[ui * 16 + sl];

    // padding_idx = 0 -> zero embedding row (ae row 0 is NOT zeroed)
    if (yi == 0) { ye.x = ye.y = ye.z = ye.w = 0.0f; }
    #pragma unroll
    for (int s = 0; s < SEQ; ++s)
        if (xi[s] == 0) { xe[s].x = xe[s].y = xe[s].z = xe[s].w = 0.0f; }

    // per-position scores
    float sc[SEQ];
    #pragma unroll
    for (int s = 0; s < SEQ; ++s) {
        const f4 a = sub_softmax(ax[s], 50.0f);
        const float fac = sub_sum(dot4(a, v4));     // aeX . (w @ aeY)
        const float dot = sub_sum(dot4(xe[s], ye)); // X_emb . y_emb
        const float tf = 1.0f - (float)(SEQ - 1 - s) * 0.1f;
        sc[s] = dot * __expf(fac) * tf;             // BETA == 1
    }

    // softmax over SEQ (identical within subgroup)
    float ms = sc[0];
    #pragma unroll
    for (int s = 1; s < SEQ; ++s) ms = fmaxf(ms, sc[s]);
    float Z = 0.0f;
    #pragma unroll
    for (int s = 0; s < SEQ; ++s) { sc[s] = __expf(sc[s] - ms); Z += sc[s]; }
    const float invZ = 1.0f / Z;

    // p = sum_s z_s*X_emb[s];  out = sigmoid((p*0.2 + u_emb) . y_emb)
    f4 p; p.x = p.y = p.z = p.w = 0.0f;
    #pragma unroll
    for (int s = 0; s < SEQ; ++s) p = fma4(xe[s], sc[s] * invZ, p);
    const f4 pu = fma4(p, 0.2f, ue);
    const float fin = sub_sum(dot4(pu, ye));
    if (live && sl == 0)
        out[b] = 1.0f / (1.0f + __expf(-fin));
}

extern "C" void kernel_launch(void* const* d_in, const int* in_sizes, int n_in,
                              void* d_out, int out_size, void* d_ws, size_t ws_size,
                              hipStream_t stream) {
    const int*   u        = (const int*)d_in[0];
    const int*   X        = (const int*)d_in[1];
    const int*   y        = (const int*)d_in[2];
    const float* item_emb = (const float*)d_in[3];
    const float* user_emb = (const float*)d_in[4];
    const float* ae_raw   = (const float*)d_in[5];
    const float* w_raw    = (const float*)d_in[6];
    float*       out      = (float*)d_out;

    float* wT = (float*)d_ws;                        // 16 KB
    float* V  = (float*)((char*)d_ws + 16384);       // B*64*4 = 4 MB

    const int B = in_sizes[0];
    const int grid = (B + 15) / 16;

    wprep_kernel<<<EMBC, EMBC, 0, stream>>>(w_raw, wT);
    vprep_kernel<<<grid, 256, 0, stream>>>(y, ae_raw, wT, V, B);
    rumc_main<<<grid, 256, 0, stream>>>(u, X, y, item_emb, user_emb,
                                        ae_raw, V, out, B);
}

// Round 5
// 141.697 us; speedup vs baseline: 1.0417x; 1.0417x over previous
//
#include <hip/hip_runtime.h>
#include <math.h>

#define SEQ 5
#define EMBC 64   // EMB == CLUSTER == 64

typedef float4 f4;

// reductions within a 16-lane subgroup (wave64 = 4 subgroups of 16)
__device__ __forceinline__ float sub_sum(float v) {
    #pragma unroll
    for (int o = 8; o > 0; o >>= 1) v += __shfl_xor(v, o, 64);
    return v;
}
__device__ __forceinline__ float sub_max(float v) {
    #pragma unroll
    for (int o = 8; o > 0; o >>= 1) v = fmaxf(v, __shfl_xor(v, o, 64));
    return v;
}
__device__ __forceinline__ float wave_max64(float v) {
    #pragma unroll
    for (int o = 32; o > 0; o >>= 1) v = fmaxf(v, __shfl_xor(v, o, 64));
    return v;
}
__device__ __forceinline__ float wave_sum64(float v) {
    #pragma unroll
    for (int o = 32; o > 0; o >>= 1) v += __shfl_xor(v, o, 64);
    return v;
}
__device__ __forceinline__ float dot4(f4 a, f4 b) {
    return fmaf(a.x, b.x, fmaf(a.y, b.y, fmaf(a.z, b.z, a.w * b.w)));
}
__device__ __forceinline__ f4 fma4(f4 a, float s, f4 c) {
    f4 r; r.x = fmaf(a.x, s, c.x); r.y = fmaf(a.y, s, c.y);
          r.z = fmaf(a.z, s, c.z); r.w = fmaf(a.w, s, c.w); return r;
}
// row softmax of a 64-float vector distributed as float4 over a 16-lane subgroup
__device__ __forceinline__ f4 sub_softmax(f4 a, float scale) {
    a.x *= scale; a.y *= scale; a.z *= scale; a.w *= scale;
    const float m = sub_max(fmaxf(fmaxf(a.x, a.y), fmaxf(a.z, a.w)));
    f4 e; e.x = __expf(a.x - m); e.y = __expf(a.y - m);
          e.z = __expf(a.z - m); e.w = __expf(a.w - m);
    const float inv = 1.0f / sub_sum(((e.x + e.y) + (e.z + e.w)));
    e.x *= inv; e.y *= inv; e.z *= inv; e.w *= inv;
    return e;
}

// ---- Kernel A: column-softmax of w_raw*500 (axis=0), stored TRANSPOSED ----
// block d (64 blocks), lane c: wT[d*64+c] = softmax_c(w_raw[:,d]*500)[c]
__global__ __launch_bounds__(64) void wprep_kernel(
    const float* __restrict__ w_raw, float* __restrict__ wT)
{
    const int d = blockIdx.x;
    const int c = threadIdx.x;
    float x = w_raw[c * EMBC + d] * 500.0f;
    const float m = wave_max64(x);
    const float e = __expf(x - m);
    const float s = wave_sum64(e);
    wT[d * EMBC + c] = e / s;   // coalesced write
}

// ---- Kernel B: main — 16 b/block; wT LDS-staged; v computed in-block ----
__global__ __launch_bounds__(256) void rumc_main(
    const int* __restrict__ u_idx, const int* __restrict__ X_idx,
    const int* __restrict__ y_idx,
    const float* __restrict__ item_emb, const float* __restrict__ user_emb,
    const float* __restrict__ ae_raw, const float* __restrict__ wT,
    float* __restrict__ out, int B)
{
    __shared__ f4 s_w[EMBC * 16];   // wT as f4: [d][c4] = d*16 + c4  (16 KB)
    __shared__ f4 s_ae[16 * 16];    // softmaxed aey per subgroup: g*16 + sl

    const int t = threadIdx.x;

    // stage wT -> LDS, coalesced (4 KB per wave-instruction)
    #pragma unroll
    for (int i = 0; i < 4; ++i)
        s_w[t + 256 * i] = ((const f4*)wT)[t + 256 * i];

    const int wave = t >> 6;
    const int lane = t & 63;
    const int sub  = lane >> 4;    // subgroup 0..3
    const int sl   = lane & 15;    // lane within subgroup
    const int g    = wave * 4 + sub;

    int b = blockIdx.x * 16 + g;
    const bool live = (b < B);
    if (!live) b = B - 1;

    // barrier BEFORE gathers so the vmcnt(0) drain doesn't kill their latency
    __syncthreads();

    // ---- indices ----
    const int yi = y_idx[b];
    const int ui = u_idx[b];
    int xi[SEQ];
    #pragma unroll
    for (int s = 0; s < SEQ; ++s) xi[s] = X_idx[b * SEQ + s];

    const f4* __restrict__ item4 = (const f4*)item_emb;
    const f4* __restrict__ user4 = (const f4*)user_emb;
    const f4* __restrict__ ae4   = (const f4*)ae_raw;

    // ---- all row gathers up front: 13 float4 loads, 1 KB/wave each ----
    f4 aey = ae4[yi * 16 + sl];
    f4 ax[SEQ];
    #pragma unroll
    for (int s = 0; s < SEQ; ++s) ax[s] = ae4[xi[s] * 16 + sl];
    f4 ye = item4[yi * 16 + sl];
    f4 xe[SEQ];
    #pragma unroll
    for (int s = 0; s < SEQ; ++s) xe[s] = item4[xi[s] * 16 + sl];
    f4 ue = user4[ui * 16 + sl];

    // padding_idx = 0 -> zero embedding row (ae row 0 is NOT zeroed)
    if (yi == 0) { ye.x = ye.y = ye.z = ye.w = 0.0f; }
    #pragma unroll
    for (int s = 0; s < SEQ; ++s)
        if (xi[s] == 0) { xe[s].x = xe[s].y = xe[s].z = xe[s].w = 0.0f; }

    // ---- aey softmax, broadcast via subgroup-private LDS line ----
    aey = sub_softmax(aey, 50.0f);
    s_ae[g * 16 + sl] = aey;       // same-wave RAW: lgkmcnt-ordered, no barrier

    // ---- v[c] = sum_d w[c][d]*aey[d]; lane sl holds c = 4sl..4sl+3 ----
    f4 v; v.x = v.y = v.z = v.w = 0.0f;
    #pragma unroll
    for (int dd = 0; dd < 16; ++dd) {
        const f4 a  = s_ae[g * 16 + dd];            // 16-lane broadcast read
        const f4 w0 = s_w[(4 * dd + 0) * 16 + sl];  // 2-way bank alias: free
        const f4 w1 = s_w[(4 * dd + 1) * 16 + sl];
        const f4 w2 = s_w[(4 * dd + 2) * 16 + sl];
        const f4 w3 = s_w[(4 * dd + 3) * 16 + sl];
        v = fma4(w0, a.x, v);
        v = fma4(w1, a.y, v);
        v = fma4(w2, a.z, v);
        v = fma4(w3, a.w, v);
    }

    // ---- per-position scores ----
    float sc[SEQ];
    #pragma unroll
    for (int s = 0; s < SEQ; ++s) {
        const f4 a = sub_softmax(ax[s], 50.0f);
        const float fac = sub_sum(dot4(a, v));      // aeX . (w @ aeY)
        const float dot = sub_sum(dot4(xe[s], ye)); // X_emb . y_emb
        const float tf = 1.0f - (float)(SEQ - 1 - s) * 0.1f;
        sc[s] = dot * __expf(fac) * tf;             // BETA == 1
    }

    // ---- softmax over SEQ (identical within subgroup) ----
    float ms = sc[0];
    #pragma unroll
    for (int s = 1; s < SEQ; ++s) ms = fmaxf(ms, sc[s]);
    float Z = 0.0f;
    #pragma unroll
    for (int s = 0; s < SEQ; ++s) { sc[s] = __expf(sc[s] - ms); Z += sc[s]; }
    const float invZ = 1.0f / Z;

    // ---- p = sum_s z_s*X_emb[s];  out = sigmoid((p*0.2 + u_emb) . y_emb) ----
    f4 p; p.x = p.y = p.z = p.w = 0.0f;
    #pragma unroll
    for (int s = 0; s < SEQ; ++s) p = fma4(xe[s], sc[s] * invZ, p);
    const f4 pu = fma4(p, 0.2f, ue);
    const float fin = sub_sum(dot4(pu, ye));
    if (live && sl == 0)
        out[b] = 1.0f / (1.0f + __expf(-fin));
}

extern "C" void kernel_launch(void* const* d_in, const int* in_sizes, int n_in,
                              void* d_out, int out_size, void* d_ws, size_t ws_size,
                              hipStream_t stream) {
    const int*   u        = (const int*)d_in[0];
    const int*   X        = (const int*)d_in[1];
    const int*   y        = (const int*)d_in[2];
    const float* item_emb = (const float*)d_in[3];
    const float* user_emb = (const float*)d_in[4];
    const float* ae_raw   = (const float*)d_in[5];
    const float* w_raw    = (const float*)d_in[6];
    float*       out      = (float*)d_out;
    float*       wT       = (float*)d_ws;   // 64*64 floats = 16 KB

    const int B = in_sizes[0];
    const int grid = (B + 15) / 16;

    wprep_kernel<<<EMBC, EMBC, 0, stream>>>(w_raw, wT);
    rumc_main<<<grid, 256, 0, stream>>>(u, X, y, item_emb, user_emb,
                                        ae_raw, wT, out, B);
}

// Round 6
// 140.966 us; speedup vs baseline: 1.0471x; 1.0052x over previous
//
#include <hip/hip_runtime.h>
#include <math.h>

#define SEQ 5
#define EMBC 64   // EMB == CLUSTER == 64

typedef float4 f4;

// ---- 16-lane subgroup reductions via DPP row_ror (VALU pipe, no LDS ops) ----
// row_ror:N ctrl = 0x120+N; rotation-reduce over 16 lanes == xor butterfly.
template<int CTRL>
__device__ __forceinline__ float dpp_rot(float v) {
    return __int_as_float(__builtin_amdgcn_update_dpp(
        0, __float_as_int(v), CTRL, 0xF, 0xF, true));
}
__device__ __forceinline__ float sub_sum(float v) {
    v += dpp_rot<0x128>(v);   // row_ror:8
    v += dpp_rot<0x124>(v);   // row_ror:4
    v += dpp_rot<0x122>(v);   // row_ror:2
    v += dpp_rot<0x121>(v);   // row_ror:1
    return v;
}
__device__ __forceinline__ float sub_max(float v) {
    v = fmaxf(v, dpp_rot<0x128>(v));
    v = fmaxf(v, dpp_rot<0x124>(v));
    v = fmaxf(v, dpp_rot<0x122>(v));
    v = fmaxf(v, dpp_rot<0x121>(v));
    return v;
}
__device__ __forceinline__ float wave_max64(float v) {
    #pragma unroll
    for (int o = 32; o > 0; o >>= 1) v = fmaxf(v, __shfl_xor(v, o, 64));
    return v;
}
__device__ __forceinline__ float wave_sum64(float v) {
    #pragma unroll
    for (int o = 32; o > 0; o >>= 1) v += __shfl_xor(v, o, 64);
    return v;
}
__device__ __forceinline__ float dot4(f4 a, f4 b) {
    return fmaf(a.x, b.x, fmaf(a.y, b.y, fmaf(a.z, b.z, a.w * b.w)));
}
__device__ __forceinline__ f4 fma4(f4 a, float s, f4 c) {
    f4 r; r.x = fmaf(a.x, s, c.x); r.y = fmaf(a.y, s, c.y);
          r.z = fmaf(a.z, s, c.z); r.w = fmaf(a.w, s, c.w); return r;
}
// row softmax of a 64-float vector distributed as float4 over a 16-lane subgroup
__device__ __forceinline__ f4 sub_softmax(f4 a, float scale) {
    a.x *= scale; a.y *= scale; a.z *= scale; a.w *= scale;
    const float m = sub_max(fmaxf(fmaxf(a.x, a.y), fmaxf(a.z, a.w)));
    f4 e; e.x = __expf(a.x - m); e.y = __expf(a.y - m);
          e.z = __expf(a.z - m); e.w = __expf(a.w - m);
    const float inv = 1.0f / sub_sum(((e.x + e.y) + (e.z + e.w)));
    e.x *= inv; e.y *= inv; e.z *= inv; e.w *= inv;
    return e;
}

// ---- Kernel A: column-softmax of w_raw*500 (axis=0), stored TRANSPOSED ----
__global__ __launch_bounds__(64) void wprep_kernel(
    const float* __restrict__ w_raw, float* __restrict__ wT)
{
    const int d = blockIdx.x;
    const int c = threadIdx.x;
    float x = w_raw[c * EMBC + d] * 500.0f;
    const float m = wave_max64(x);
    const float e = __expf(x - m);
    const float s = wave_sum64(e);
    wT[d * EMBC + c] = e / s;   // coalesced write
}

// ---- Kernel B: main — 16 b/block; wT LDS-staged; v computed in-block ----
__global__ __launch_bounds__(256) void rumc_main(
    const int* __restrict__ u_idx, const int* __restrict__ X_idx,
    const int* __restrict__ y_idx,
    const float* __restrict__ item_emb, const float* __restrict__ user_emb,
    const float* __restrict__ ae_raw, const float* __restrict__ wT,
    float* __restrict__ out, int B)
{
    __shared__ f4 s_w[EMBC * 16];   // wT as f4: [d][c4] = d*16 + c4  (16 KB)
    __shared__ f4 s_ae[16 * 16];    // softmaxed aey per subgroup: g*16 + sl

    const int t = threadIdx.x;

    // stage wT -> LDS, coalesced (4 KB per wave-instruction)
    #pragma unroll
    for (int i = 0; i < 4; ++i)
        s_w[t + 256 * i] = ((const f4*)wT)[t + 256 * i];

    const int wave = t >> 6;
    const int lane = t & 63;
    const int sub  = lane >> 4;    // subgroup 0..3
    const int sl   = lane & 15;    // lane within subgroup
    const int g    = wave * 4 + sub;

    int b = blockIdx.x * 16 + g;
    const bool live = (b < B);
    if (!live) b = B - 1;

    // barrier BEFORE gathers so the vmcnt(0) drain doesn't kill their latency
    __syncthreads();

    // ---- indices ----
    const int yi = y_idx[b];
    const int ui = u_idx[b];
    int xi[SEQ];
    #pragma unroll
    for (int s = 0; s < SEQ; ++s) xi[s] = X_idx[b * SEQ + s];

    const f4* __restrict__ item4 = (const f4*)item_emb;
    const f4* __restrict__ user4 = (const f4*)user_emb;
    const f4* __restrict__ ae4   = (const f4*)ae_raw;

    // ---- all row gathers up front: 13 float4 loads, 1 KB/wave each ----
    f4 aey = ae4[yi * 16 + sl];
    f4 ax[SEQ];
    #pragma unroll
    for (int s = 0; s < SEQ; ++s) ax[s] = ae4[xi[s] * 16 + sl];
    f4 ye = item4[yi * 16 + sl];
    f4 xe[SEQ];
    #pragma unroll
    for (int s = 0; s < SEQ; ++s) xe[s] = item4[xi[s] * 16 + sl];
    f4 ue = user4[ui * 16 + sl];

    // padding_idx = 0 -> zero embedding row (ae row 0 is NOT zeroed)
    if (yi == 0) { ye.x = ye.y = ye.z = ye.w = 0.0f; }
    #pragma unroll
    for (int s = 0; s < SEQ; ++s)
        if (xi[s] == 0) { xe[s].x = xe[s].y = xe[s].z = xe[s].w = 0.0f; }

    // ---- aey softmax, broadcast via subgroup-private LDS line ----
    aey = sub_softmax(aey, 50.0f);
    s_ae[g * 16 + sl] = aey;       // same-wave RAW: lgkmcnt-ordered, no barrier

    // ---- v[c] = sum_d w[c][d]*aey[d]; lane sl holds c = 4sl..4sl+3 ----
    f4 v; v.x = v.y = v.z = v.w = 0.0f;
    #pragma unroll
    for (int dd = 0; dd < 16; ++dd) {
        const f4 a  = s_ae[g * 16 + dd];            // 16-lane broadcast read
        const f4 w0 = s_w[(4 * dd + 0) * 16 + sl];  // 2-way bank alias: free
        const f4 w1 = s_w[(4 * dd + 1) * 16 + sl];
        const f4 w2 = s_w[(4 * dd + 2) * 16 + sl];
        const f4 w3 = s_w[(4 * dd + 3) * 16 + sl];
        v = fma4(w0, a.x, v);
        v = fma4(w1, a.y, v);
        v = fma4(w2, a.z, v);
        v = fma4(w3, a.w, v);
    }

    // ---- per-position scores ----
    float sc[SEQ];
    #pragma unroll
    for (int s = 0; s < SEQ; ++s) {
        const f4 a = sub_softmax(ax[s], 50.0f);
        const float fac = sub_sum(dot4(a, v));      // aeX . (w @ aeY)
        const float dot = sub_sum(dot4(xe[s], ye)); // X_emb . y_emb
        const float tf = 1.0f - (float)(SEQ - 1 - s) * 0.1f;
        sc[s] = dot * __expf(fac) * tf;             // BETA == 1
    }

    // ---- softmax over SEQ (identical within subgroup) ----
    float ms = sc[0];
    #pragma unroll
    for (int s = 1; s < SEQ; ++s) ms = fmaxf(ms, sc[s]);
    float Z = 0.0f;
    #pragma unroll
    for (int s = 0; s < SEQ; ++s) { sc[s] = __expf(sc[s] - ms); Z += sc[s]; }
    const float invZ = 1.0f / Z;

    // ---- p = sum_s z_s*X_emb[s];  out = sigmoid((p*0.2 + u_emb) . y_emb) ----
    f4 p; p.x = p.y = p.z = p.w = 0.0f;
    #pragma unroll
    for (int s = 0; s < SEQ; ++s) p = fma4(xe[s], sc[s] * invZ, p);
    const f4 pu = fma4(p, 0.2f, ue);
    const float fin = sub_sum(dot4(pu, ye));
    if (live && sl == 0)
        out[b] = 1.0f / (1.0f + __expf(-fin));
}

extern "C" void kernel_launch(void* const* d_in, const int* in_sizes, int n_in,
                              void* d_out, int out_size, void* d_ws, size_t ws_size,
                              hipStream_t stream) {
    const int*   u        = (const int*)d_in[0];
    const int*   X        = (const int*)d_in[1];
    const int*   y        = (const int*)d_in[2];
    const float* item_emb = (const float*)d_in[3];
    const float* user_emb = (const float*)d_in[4];
    const float* ae_raw   = (const float*)d_in[5];
    const float* w_raw    = (const float*)d_in[6];
    float*       out      = (float*)d_out;
    float*       wT       = (float*)d_ws;   // 64*64 floats = 16 KB

    const int B = in_sizes[0];
    const int grid = (B + 15) / 16;

    wprep_kernel<<<EMBC, EMBC, 0, stream>>>(w_raw, wT);
    rumc_main<<<grid, 256, 0, stream>>>(u, X, y, item_emb, user_emb,
                                        ae_raw, wT, out, B);
}